// Round 5
// baseline (866.068 us; speedup 1.0000x reference)
//
#include <hip/hip_runtime.h>
#include <hip/hip_bf16.h>

// EdgePredictor: gather-concat -> Linear(320->256) -> BatchNorm(train) ->
// Linear(256->8) -> LogSoftmax.  Float tensors FP32; output FP32.
// Indices int32 or int64 -> runtime detect.
//
// Algebra: logits = h @ M^T + C,  M = W2*diag(g')*W1 (8x320).
// Split along concat: logits_e = ef_e @ Me^T + Ps[src_e] + Pd[dst_e] + C.
//
// Round-5 structure: BARRIER-FREE K-loop in pass A (direct-from-global MFMA
// A-frags, 3-deep rolling nf prefetch, hoisted ef/B prefetch) — the per-slice
// __syncthreads in rounds 3/4 forced a vmcnt(0) drain of all prefetch every
// iteration (m97 plateau mechanism). nf pre-converted to bf16 (halves gather).

#define N_EDGES 800000
#define N_NODES 50000

typedef __attribute__((ext_vector_type(8))) short short8;
typedef __attribute__((ext_vector_type(4))) float f32x4;

// ws layout (bytes)
#define WS_SUM   0         // 16 slots x 256 f32
#define WS_SQ    16384
#define WS_CVEC  32768     // 16 f32
#define WS_FLAG  32832     // 1 int (pad to 33280)
#define WS_MBIG  33280     // 16 x 320 bf16 (fallback out_kernel)
#define WS_MB    43520     // 16 x 64 bf16 (edge part of M)
#define WS_MF    45568     // 8 x 320 f32
#define WS_W1B   55808     // 256 x 320 bf16 = 163840 -> 219648
#define WS_PS    262144    // 50000 x 8 f32 (+pad) = 1600064
#define WS_PD    2097152   // -> 3697216
#define WS_NFB   4194304   // 50000 x 128 bf16 = 12800000 -> 16994304
#define WS_MID_NEED  (4u << 20)
#define WS_V3_NEED   (4194304u + 12800000u)

__device__ __forceinline__ ushort f2bf(float f) {
    union { float f; unsigned int u; } x; x.f = f;
    unsigned int r = x.u + 0x7FFFu + ((x.u >> 16) & 1u);   // RNE
    return (ushort)(r >> 16);
}
__device__ __forceinline__ short8 cvt8(const float* __restrict__ p) {
    short8 r;
    #pragma unroll
    for (int i = 0; i < 8; i++) r[i] = (short)f2bf(p[i]);
    return r;
}
__device__ __forceinline__ short8 cvtpair(uint4 a, uint4 b) {
    unsigned int v[8] = {a.x, a.y, a.z, a.w, b.x, b.y, b.z, b.w};
    short8 r;
    #pragma unroll
    for (int i = 0; i < 8; i++) {
        unsigned int u = v[i];
        unsigned int rr = u + 0x7FFFu + ((u >> 16) & 1u);
        r[i] = (short)(rr >> 16);
    }
    return r;
}

// -------- detect index width: int64 iff all sampled high words are zero ----
__global__ void detect_kernel(const int* __restrict__ src,
                              const int* __restrict__ dst, int* flag) {
    int t = threadIdx.x;
    int v = src[2 * t + 1] | dst[2 * t + 1];
    #pragma unroll
    for (int o = 32; o >= 1; o >>= 1) v |= __shfl_xor(v, o);
    if (t == 0) *flag = (v == 0) ? 1 : 0;
}

// -------- prep: W1 f32 -> bf16 --------
__global__ __launch_bounds__(256) void prep_kernel(const float* __restrict__ W1,
                                                   ushort* __restrict__ W1b) {
    const int i = (blockIdx.x * 256 + threadIdx.x) * 4;
    const float4 v = *(const float4*)(W1 + i);
    ushort4 o;
    o.x = f2bf(v.x); o.y = f2bf(v.y); o.z = f2bf(v.z); o.w = f2bf(v.w);
    *(ushort4*)(W1b + i) = o;
}

// -------- prep: nf f32 -> bf16 (12.8 MB) --------
__global__ __launch_bounds__(256) void prep_nf_kernel(const float* __restrict__ nf,
                                                      ushort* __restrict__ nfb) {
    const int i = (blockIdx.x * 256 + threadIdx.x) * 4;   // 6.4M elems
    const float4 v = *(const float4*)(nf + i);
    ushort4 o;
    o.x = f2bf(v.x); o.y = f2bf(v.y); o.z = f2bf(v.z); o.w = f2bf(v.w);
    *(ushort4*)(nfb + i) = o;
}

// ---------------- Pass A v3: barrier-free gather+GEMM1+stats ----------------
// grid 12500, block 256 (4 waves). Per wave: 64 edges x 64 cols, K=320 (10x32).
// A-frags direct from global: ef (f32, hoisted) / nfb (bf16, 3-deep pipeline).
__global__ __launch_bounds__(256) void gemm1_stats_v3(
    const float* __restrict__ ef, const ushort* __restrict__ nfb,
    const int* __restrict__ src, const int* __restrict__ dst,
    const ushort* __restrict__ W1b, const int* __restrict__ flag,
    float* __restrict__ g_sum, float* __restrict__ g_sq)
{
    __shared__ float s_sum[256];
    __shared__ float s_sq[256];

    const int t    = threadIdx.x;
    const int lane = t & 63;
    const int wave = t >> 6;
    const int quad = lane >> 4;
    const int l15  = lane & 15;

    s_sum[t] = 0.f; s_sq[t] = 0.f;
    __syncthreads();                       // init visible before epilogue atomics

    const int wide = *flag;
    const long e0 = (long)blockIdx.x * 64;

    // per-lane row pointers for the 4 row-blocks (edges mb*16 + l15)
    const float*  pef[4];
    const ushort* pns[4];
    const ushort* pnd[4];
    #pragma unroll
    for (int mb = 0; mb < 4; mb++) {
        const long e = e0 + mb * 16 + l15;
        const int si = src[e << wide], di = dst[e << wide];
        pef[mb] = ef + e * 64;
        pns[mb] = nfb + (long)si * 128;
        pnd[mb] = nfb + (long)di * 128;
    }

    // hoist ef frag loads (slices 0,1): 8 x 32 B per lane
    uint4 efr[2][4][2];
    #pragma unroll
    for (int ks = 0; ks < 2; ks++)
        #pragma unroll
        for (int mb = 0; mb < 4; mb++) {
            const float* p = pef[mb] + ks * 32 + quad * 8;
            efr[ks][mb][0] = *(const uint4*)p;
            efr[ks][mb][1] = *(const uint4*)(p + 4);
        }

    // nf pipeline: preload slices 2,3,4 (all in src segment)
    short8 anf[3][4];
    #pragma unroll
    for (int d = 0; d < 3; d++)
        #pragma unroll
        for (int mb = 0; mb < 4; mb++)
            anf[d][mb] = *(const short8*)(pns[mb] + (2 + d) * 32 - 64 + quad * 8);

    // B frags: current + next
    const ushort* wbase = W1b + (wave * 64 + l15) * 320 + quad * 8;
    short8 bfr[4], bnx[4];
    #pragma unroll
    for (int in = 0; in < 4; in++)
        bfr[in] = *(const short8*)(wbase + in * 16 * 320);

    f32x4 acc[4][4];
    #pragma unroll
    for (int a = 0; a < 4; a++)
        #pragma unroll
        for (int b = 0; b < 4; b++) acc[a][b] = (f32x4){0.f, 0.f, 0.f, 0.f};

    #pragma unroll
    for (int ks = 0; ks < 10; ks++) {
        if (ks < 9)                        // prefetch B for ks+1
            #pragma unroll
            for (int in = 0; in < 4; in++)
                bnx[in] = *(const short8*)(wbase + in * 16 * 320 + (ks + 1) * 32);

        short8 a[4];
        if (ks < 2) {
            #pragma unroll
            for (int mb = 0; mb < 4; mb++)
                a[mb] = cvtpair(efr[ks][mb][0], efr[ks][mb][1]);
        } else {
            #pragma unroll
            for (int mb = 0; mb < 4; mb++) a[mb] = anf[(ks - 2) % 3][mb];
        }

        #pragma unroll
        for (int mb = 0; mb < 4; mb++)
            #pragma unroll
            for (int in = 0; in < 4; in++)
                acc[mb][in] = __builtin_amdgcn_mfma_f32_16x16x32_bf16(
                    a[mb], bfr[in], acc[mb][in], 0, 0, 0);

        if (ks >= 2 && ks <= 6) {          // refill slot with slice ks+3
            const int s = ks + 3;
            #pragma unroll
            for (int mb = 0; mb < 4; mb++)
                anf[(ks + 1) % 3][mb] = (s < 6)
                    ? *(const short8*)(pns[mb] + s * 32 - 64  + quad * 8)
                    : *(const short8*)(pnd[mb] + s * 32 - 192 + quad * 8);
        }
        if (ks < 9)
            #pragma unroll
            for (int in = 0; in < 4; in++) bfr[in] = bnx[in];
    }

    // Stats on acc = z - b1 (b1 folded later; var shift-invariant).
    #pragma unroll
    for (int in = 0; in < 4; in++) {
        const int col = wave * 64 + in * 16 + l15;
        float s = 0.f, q = 0.f;
        #pragma unroll
        for (int mb = 0; mb < 4; mb++)
            #pragma unroll
            for (int j = 0; j < 4; j++) {
                float v = acc[mb][in][j];
                s += v; q += v * v;
            }
        s += __shfl_xor(s, 16); s += __shfl_xor(s, 32);
        q += __shfl_xor(q, 16); q += __shfl_xor(q, 32);
        if (quad == 0) { atomicAdd(&s_sum[col], s); atomicAdd(&s_sq[col], q); }
    }
    __syncthreads();
    const int slot = blockIdx.x & 15;
    atomicAdd(&g_sum[slot * 256 + t], s_sum[t]);
    atomicAdd(&g_sq[slot * 256 + t], s_sq[t]);
}

// ---------------- Pass A fallback (round-4 LDS version) ----------------
__global__ __launch_bounds__(256) void gemm1_stats_kernel(
    const float* __restrict__ nf, const float* __restrict__ ef,
    const int* __restrict__ src, const int* __restrict__ dst,
    const ushort* __restrict__ W1b, const int* __restrict__ flag,
    float* __restrict__ g_sum, float* __restrict__ g_sq)
{
    __shared__ ushort a_lds[2][64 * 40];
    __shared__ float s_sum[256];
    __shared__ float s_sq[256];

    const int t    = threadIdx.x;
    const int lane = t & 63;
    const int wave = t >> 6;
    const int quad = lane >> 4;
    const int l15  = lane & 15;

    s_sum[t] = 0.f; s_sq[t] = 0.f;

    const int wide = *flag;
    const int r = t >> 2, chunk = t & 3;
    const long e  = (long)blockIdx.x * 64 + r;
    const int si = src[e << wide], di = dst[e << wide];
    const float* pe = ef + e * 64 + chunk * 8;
    const float* ps = nf + (long)si * 128 + chunk * 8;
    const float* pd = nf + (long)di * 128 + chunk * 8;

    {
        const float* p0 = pe;
        *(short8*)&a_lds[0][r * 40 + chunk * 8] =
            cvtpair(*(const uint4*)p0, *(const uint4*)(p0 + 4));
    }
    __syncthreads();

    f32x4 acc[4][4];
    #pragma unroll
    for (int a = 0; a < 4; a++)
        #pragma unroll
        for (int b = 0; b < 4; b++) acc[a][b] = (f32x4){0.f, 0.f, 0.f, 0.f};

    const ushort* wbase = W1b + (wave * 64 + l15) * 320 + quad * 8;

    #pragma unroll
    for (int ks = 0; ks < 10; ks++) {
        if (ks < 9) {
            const int kn = ks + 1;
            const float* p = (kn < 2) ? (pe + kn * 32)
                           : (kn < 6) ? (ps + (kn * 32 - 64))
                                      : (pd + (kn * 32 - 192));
            *(short8*)&a_lds[(ks + 1) & 1][r * 40 + chunk * 8] =
                cvtpair(*(const uint4*)p, *(const uint4*)(p + 4));
        }
        short8 bfr[4];
        #pragma unroll
        for (int in = 0; in < 4; in++)
            bfr[in] = *(const short8*)(wbase + in * 16 * 320 + ks * 32);
        #pragma unroll
        for (int mb = 0; mb < 4; mb++) {
            short8 afr = *(const short8*)
                &a_lds[ks & 1][(mb * 16 + l15) * 40 + quad * 8];
            #pragma unroll
            for (int in = 0; in < 4; in++)
                acc[mb][in] = __builtin_amdgcn_mfma_f32_16x16x32_bf16(
                    afr, bfr[in], acc[mb][in], 0, 0, 0);
        }
        __syncthreads();
    }

    #pragma unroll
    for (int in = 0; in < 4; in++) {
        const int col = wave * 64 + in * 16 + l15;
        float s = 0.f, q = 0.f;
        #pragma unroll
        for (int mb = 0; mb < 4; mb++)
            #pragma unroll
            for (int j = 0; j < 4; j++) {
                float v = acc[mb][in][j];
                s += v; q += v * v;
            }
        s += __shfl_xor(s, 16); s += __shfl_xor(s, 32);
        q += __shfl_xor(q, 16); q += __shfl_xor(q, 32);
        if (quad == 0) { atomicAdd(&s_sum[col], s); atomicAdd(&s_sq[col], q); }
    }
    __syncthreads();
    const int slot = blockIdx.x & 15;
    atomicAdd(&g_sum[slot * 256 + t], s_sum[t]);
    atomicAdd(&g_sq[slot * 256 + t], s_sq[t]);
}

// ---------------- fold stats into M / C ----------------
__global__ __launch_bounds__(256) void fold_kernel(
    const float* __restrict__ gamma, const float* __restrict__ beta,
    const float* __restrict__ W1, const float* __restrict__ b1,
    const float* __restrict__ W2, const float* __restrict__ b2,
    const float* __restrict__ g_sum, const float* __restrict__ g_sq,
    ushort* __restrict__ Mbig, ushort* __restrict__ Mb,
    float* __restrict__ Mf, float* __restrict__ Cvec)
{
    __shared__ float a_sh[256][8];
    __shared__ float red[8];
    const int h = threadIdx.x;

    float ssum = 0.f, ssq = 0.f;
    #pragma unroll
    for (int s = 0; s < 16; s++) {
        ssum += g_sum[s * 256 + h];
        ssq  += g_sq[s * 256 + h];
    }
    const float invE   = 1.0f / (float)N_EDGES;
    const float mu_acc = ssum * invE;
    float var = ssq * invE - mu_acc * mu_acc;
    var = fmaxf(var, 0.f);
    const float b1v = b1[h];
    const float mu  = mu_acc + b1v;
    const float g   = gamma[h] * rsqrtf(var + 1e-5f);
    const float sh  = b1v * g + beta[h] - mu * g;

    if (h < 8) red[h] = 0.f;
    __syncthreads();
    #pragma unroll
    for (int c = 0; c < 8; c++) {
        const float w = W2[c * 256 + h];
        a_sh[h][c] = w * g;
        atomicAdd(&red[c], w * sh);
    }
    __syncthreads();

    for (int k = h; k < 320; k += 256) {
        float m[8] = {0.f, 0.f, 0.f, 0.f, 0.f, 0.f, 0.f, 0.f};
        for (int hh = 0; hh < 256; hh++) {
            const float w1 = W1[hh * 320 + k];
            #pragma unroll
            for (int c = 0; c < 8; c++) m[c] += a_sh[hh][c] * w1;
        }
        #pragma unroll
        for (int c = 0; c < 8; c++) {
            Mf[c * 320 + k]   = m[c];
            Mbig[c * 320 + k] = f2bf(m[c]);
            if (k < 64) Mb[c * 64 + k] = f2bf(m[c]);
        }
        #pragma unroll
        for (int c = 8; c < 16; c++) {
            Mbig[c * 320 + k] = 0;
            if (k < 64) Mb[c * 64 + k] = 0;
        }
    }
    if (h < 8)       Cvec[h] = b2[h] + red[h];
    else if (h < 16) Cvec[h] = 0.f;
}

// ---------------- node projection tables ----------------
__global__ __launch_bounds__(256) void nodeproj_kernel(
    const float* __restrict__ nf, const float* __restrict__ Mf,
    float* __restrict__ Ps, float* __restrict__ Pd)
{
    __shared__ float Ms[8][128];
    __shared__ float Md[8][128];
    const int t = threadIdx.x;
    #pragma unroll
    for (int i = 0; i < 4; i++) {
        const int f = t + i * 256;
        Ms[f >> 7][f & 127] = Mf[(f >> 7) * 320 + 64  + (f & 127)];
        Md[f >> 7][f & 127] = Mf[(f >> 7) * 320 + 192 + (f & 127)];
    }
    __syncthreads();
    const int n = blockIdx.x * 256 + t;
    if (n >= N_NODES) return;
    float as[8] = {0,0,0,0,0,0,0,0}, ad[8] = {0,0,0,0,0,0,0,0};
    for (int k = 0; k < 128; k += 4) {
        const float4 v = *(const float4*)(nf + (long)n * 128 + k);
        #pragma unroll
        for (int c = 0; c < 8; c++) {
            const float4 ms = *(const float4*)&Ms[c][k];
            const float4 md = *(const float4*)&Md[c][k];
            as[c] += v.x * ms.x + v.y * ms.y + v.z * ms.z + v.w * ms.w;
            ad[c] += v.x * md.x + v.y * md.y + v.z * md.z + v.w * md.w;
        }
    }
    #pragma unroll
    for (int c = 0; c < 8; c++) {
        Ps[n * 8 + c] = as[c];
        Pd[n * 8 + c] = ad[c];
    }
}

// ---------------- output pass v2: ef GEMM + tables + log-softmax ----------
__global__ __launch_bounds__(256) void edge_out_v2(
    const float* __restrict__ ef, const int* __restrict__ src,
    const int* __restrict__ dst, const int* __restrict__ flag,
    const ushort* __restrict__ Mb, const float* __restrict__ Ps,
    const float* __restrict__ Pd, const float* __restrict__ Cvec,
    float* __restrict__ out)
{
    const int t    = threadIdx.x;
    const int lane = t & 63;
    const int wave = t >> 6;
    const int quad = lane >> 4;
    const int l15  = lane & 15;
    const int wide = *flag;
    const long eb  = (long)blockIdx.x * 256 + wave * 64;

    // wave-coalesced index loads: lane holds edge eb+lane
    const long eli = (eb + lane) << wide;
    const int s_all = src[eli];
    const int d_all = dst[eli];

    // hoist ef frag loads
    uint4 er[2][4][2];
    #pragma unroll
    for (int ks = 0; ks < 2; ks++)
        #pragma unroll
        for (int mb = 0; mb < 4; mb++) {
            const float* p = ef + (eb + mb * 16 + l15) * 64 + ks * 32 + quad * 8;
            er[ks][mb][0] = *(const uint4*)p;
            er[ks][mb][1] = *(const uint4*)(p + 4);
        }
    short8 bfr[2];
    #pragma unroll
    for (int ks = 0; ks < 2; ks++)
        bfr[ks] = *(const short8*)(Mb + l15 * 64 + ks * 32 + quad * 8);

    f32x4 acc[4];
    #pragma unroll
    for (int mb = 0; mb < 4; mb++) acc[mb] = (f32x4){0.f, 0.f, 0.f, 0.f};
    #pragma unroll
    for (int ks = 0; ks < 2; ks++)
        #pragma unroll
        for (int mb = 0; mb < 4; mb++)
            acc[mb] = __builtin_amdgcn_mfma_f32_16x16x32_bf16(
                cvtpair(er[ks][mb][0], er[ks][mb][1]), bfr[ks], acc[mb], 0, 0, 0);

    // table phase: shfl indices, issue all 32 loads before softmax chain
    float pv[4][4];
    #pragma unroll
    for (int mb = 0; mb < 4; mb++)
        #pragma unroll
        for (int j = 0; j < 4; j++) {
            const int row = mb * 16 + quad * 4 + j;
            const int sx = __shfl(s_all, row);
            const int dx = __shfl(d_all, row);
            pv[mb][j] = Ps[sx * 8 + l15] + Pd[dx * 8 + l15];  // l15>=8: junk, safe
        }

    const float bv = Cvec[l15];
    #pragma unroll
    for (int mb = 0; mb < 4; mb++)
        #pragma unroll
        for (int j = 0; j < 4; j++) {
            float x = acc[mb][j] + bv + pv[mb][j];
            float m = x;
            m = fmaxf(m, __shfl_xor(m, 1));
            m = fmaxf(m, __shfl_xor(m, 2));
            m = fmaxf(m, __shfl_xor(m, 4));
            float sx = __expf(x - m);
            sx += __shfl_xor(sx, 1);
            sx += __shfl_xor(sx, 2);
            sx += __shfl_xor(sx, 4);
            const float o = x - m - __logf(sx);
            if (l15 < 8)
                out[(eb + mb * 16 + quad * 4 + j) * 8 + l15] = o;
        }
}

// ---------------- output fallback: full gather ----------------
__global__ __launch_bounds__(256) void out_kernel(
    const float* __restrict__ nf, const float* __restrict__ ef,
    const int* __restrict__ src, const int* __restrict__ dst,
    const int* __restrict__ flag, const ushort* __restrict__ M,
    const float* __restrict__ Cvec, float* __restrict__ out)
{
    const int t    = threadIdx.x;
    const int lane = t & 63;
    const int wave = t >> 6;
    const int quad = lane >> 4;
    const int l15  = lane & 15;
    const int wide = *flag;
    const long eb  = (long)blockIdx.x * 256 + wave * 64;

    const float* pe[4]; const float* ps[4]; const float* pd[4];
    #pragma unroll
    for (int mb = 0; mb < 4; mb++) {
        const long e  = eb + mb * 16 + l15;
        const int si = src[e << wide], di = dst[e << wide];
        pe[mb] = ef + e * 64;
        ps[mb] = nf + (long)si * 128;
        pd[mb] = nf + (long)di * 128;
    }
    f32x4 acc[4];
    #pragma unroll
    for (int mb = 0; mb < 4; mb++) acc[mb] = (f32x4){0.f, 0.f, 0.f, 0.f};
    const ushort* bbase = M + l15 * 320 + quad * 8;
    #pragma unroll
    for (int ks = 0; ks < 10; ks++) {
        const int k0 = ks * 32;
        short8 bfr = *(const short8*)(bbase + k0);
        const int koff = k0 + quad * 8;
        #pragma unroll
        for (int mb = 0; mb < 4; mb++) {
            const float* p = (ks < 2) ? (pe[mb] + koff)
                           : (ks < 6) ? (ps[mb] + (koff - 64))
                                      : (pd[mb] + (koff - 192));
            acc[mb] = __builtin_amdgcn_mfma_f32_16x16x32_bf16(
                cvt8(p), bfr, acc[mb], 0, 0, 0);
        }
    }
    const float bv = Cvec[l15];
    #pragma unroll
    for (int mb = 0; mb < 4; mb++)
        #pragma unroll
        for (int j = 0; j < 4; j++) {
            float x = acc[mb][j] + bv;
            float m = x;
            m = fmaxf(m, __shfl_xor(m, 1));
            m = fmaxf(m, __shfl_xor(m, 2));
            m = fmaxf(m, __shfl_xor(m, 4));
            float sx = __expf(x - m);
            sx += __shfl_xor(sx, 1);
            sx += __shfl_xor(sx, 2);
            sx += __shfl_xor(sx, 4);
            const float o = x - m - __logf(sx);
            if (l15 < 8)
                out[(eb + mb * 16 + quad * 4 + j) * 8 + l15] = o;
        }
}

extern "C" void kernel_launch(void* const* d_in, const int* in_sizes, int n_in,
                              void* d_out, int out_size, void* d_ws, size_t ws_size,
                              hipStream_t stream) {
    const float* nf    = (const float*)d_in[0];
    const float* ef    = (const float*)d_in[1];
    const int*   src   = (const int*)d_in[2];
    const int*   dst   = (const int*)d_in[3];
    const float* W1    = (const float*)d_in[4];
    const float* b1    = (const float*)d_in[5];
    const float* gamma = (const float*)d_in[6];
    const float* beta  = (const float*)d_in[7];
    const float* W2    = (const float*)d_in[8];
    const float* b2    = (const float*)d_in[9];

    char*   ws    = (char*)d_ws;
    float*  g_sum = (float*)(ws + WS_SUM);
    float*  g_sq  = (float*)(ws + WS_SQ);
    float*  Cvec  = (float*)(ws + WS_CVEC);
    int*    flag  = (int*)(ws + WS_FLAG);
    ushort* Mbig  = (ushort*)(ws + WS_MBIG);
    ushort* Mb    = (ushort*)(ws + WS_MB);
    float*  Mf    = (float*)(ws + WS_MF);
    ushort* W1b   = (ushort*)(ws + WS_W1B);
    float*  Ps    = (float*)(ws + WS_PS);
    float*  Pd    = (float*)(ws + WS_PD);
    ushort* nfb   = (ushort*)(ws + WS_NFB);
    float*  out   = (float*)d_out;

    hipMemsetAsync(ws, 0, 33280, stream);
    detect_kernel<<<1, 64, 0, stream>>>(src, dst, flag);
    prep_kernel<<<80, 256, 0, stream>>>(W1, W1b);

    if (ws_size >= WS_V3_NEED) {
        prep_nf_kernel<<<6250, 256, 0, stream>>>(nf, nfb);   // 6.4M elems
        gemm1_stats_v3<<<N_EDGES / 64, 256, 0, stream>>>(ef, nfb, src, dst,
                                                         W1b, flag, g_sum, g_sq);
    } else {
        gemm1_stats_kernel<<<N_EDGES / 64, 256, 0, stream>>>(nf, ef, src, dst,
                                                             W1b, flag, g_sum, g_sq);
    }
    fold_kernel<<<1, 256, 0, stream>>>(gamma, beta, W1, b1, W2, b2,
                                       g_sum, g_sq, Mbig, Mb, Mf, Cvec);
    if (ws_size >= WS_MID_NEED) {
        nodeproj_kernel<<<(N_NODES + 255) / 256, 256, 0, stream>>>(nf, Mf, Ps, Pd);
        edge_out_v2<<<N_EDGES / 256, 256, 0, stream>>>(ef, src, dst, flag,
                                                       Mb, Ps, Pd, Cvec, out);
    } else {
        out_kernel<<<N_EDGES / 256, 256, 0, stream>>>(nf, ef, src, dst, flag,
                                                      Mbig, Cvec, out);
    }
}